// Round 1
// baseline (562.940 us; speedup 1.0000x reference)
//
#include <hip/hip_runtime.h>

// Problem constants (from reference)
constexpr int Kk   = 21;
constexpr int Hh   = 512, Ww = 512;
constexpr int HO   = 492, WO = 492;          // valid conv output dims
constexpr int Cc   = 10;                     // center offset
constexpr int CTRi = 220;                    // center channel idx (dropped)
constexpr int NCH  = 440;                    // K*K - 1
constexpr int ROW4 = WO / 4;                 // 123 float4 per w row (exact, 16B aligned)
constexpr int N4F  = Hh * Ww / 4;            // 65,536 float4s for fidelity

// New decomposition: block = (plane, row-slab). w is read fully sequentially
// per block (426 MB total, one pass): fixes HBM row-buffer + TLB locality.
constexpr int SLABS     = 6;                 // row slabs per plane
constexpr int SLAB_ROWS = HO / SLABS;        // 82 rows per slab (exact)
constexpr int ITERS     = SLAB_ROWS / 2;     // 41 two-row iterations
constexpr int NBLK      = NCH * SLABS;       // 2640 blocks

constexpr float SCALE_S  = (float)((512.0 * 512.0 * 128.0) / (440.0 * 492.0 * 492.0));
constexpr float FID_RATIO = (float)((1.0 / (512.0 * 512.0)) /
                                    ((512.0 * 512.0 * 128.0) / (440.0 * 492.0 * 492.0)));

typedef float floatx4  __attribute__((ext_vector_type(4)));              // 16B aligned
typedef float floatx4u __attribute__((ext_vector_type(4), aligned(4)));  // unaligned-ok

#define TPB 256

__device__ __forceinline__ float block_reduce_256(float v) {
    #pragma unroll
    for (int off = 32; off; off >>= 1) v += __shfl_down(v, off, 64);
    __shared__ float smem[TPB / 64];
    const int lane = threadIdx.x & 63;
    const int wid  = threadIdx.x >> 6;
    if (lane == 0) smem[wid] = v;
    __syncthreads();
    float r = 0.f;
    if (threadIdx.x == 0) {
        #pragma unroll
        for (int k = 0; k < TPB / 64; ++k) r += smem[k];
    }
    return r;
}

// One block: one w-plane (fixed channel n) x 82-row slab.
// 246 active threads cover 2 rows = 3936 CONTIGUOUS bytes of w per iter;
// iterations advance linearly -> each block streams a sequential 161 KB slab.
// ki/kj/bias are block-uniform scalars. Center+neighbor taps come from the
// 1 MB outp image (L2-resident; w uses nontemporal loads so it never evicts it).
__global__ __launch_bounds__(TPB) void main_kernel(
        const float* __restrict__ outp,
        const float* __restrict__ targ,
        const float* __restrict__ w,
        const float* __restrict__ bias,
        float* __restrict__ partial)
{
    const int t = threadIdx.x;
    float acc = 0.f;

    // ---- fused fidelity: first N4F global threads take one float4 each ----
    {
        const int fq = blockIdx.x * TPB + t;
        if (fq < N4F) {
            const floatx4 a  = ((const floatx4*)outp)[fq];
            const floatx4 tg = ((const floatx4*)targ)[fq];
            const float d0 = a.x - tg.x, d1 = a.y - tg.y,
                        d2 = a.z - tg.z, d3 = a.w - tg.w;
            acc = (d0 * d0 + d1 * d1 + d2 * d2 + d3 * d3) * FID_RATIO;
        }
    }

    // ---- smooth term: sequential stream over one plane-slab of w ----
    const int plane = blockIdx.x / SLABS;     // channel n, 0..439
    const int slab  = blockIdx.x % SLABS;

    if (t < 2 * ROW4) {                       // 246 active threads
        const int kk = plane + (plane >= CTRi ? 1 : 0);   // skip dropped center
        const int ki = kk / Kk;                            // block-uniform
        const int kj = kk - ki * Kk;
        const float b = bias[plane];                       // block-uniform

        const int i0 = slab * SLAB_ROWS;      // first w-plane row of this slab
        const int r  = t / ROW4;              // 0 or 1: which of the 2 rows
        const int j  = 4 * (t - r * ROW4);    // w-plane col (float units)

        // w: flat contiguous — thread t reads float4 (i0*123 + t) of plane
        const floatx4* wp = (const floatx4*)w + ((long)plane * HO + i0) * ROW4 + t;
        // center tap row / neighbor tap row in outp
        const float* cp = outp + (i0 + r + Cc) * Ww + (Cc + j);
        const float* np = outp + (i0 + r + ki) * Ww + (kj + j);

        float a0 = 0.f, a1 = 0.f, a2 = 0.f, a3 = 0.f;
        #pragma unroll 4
        for (int it = 0; it < ITERS; ++it) {
            const floatx4  w4 = __builtin_nontemporal_load(wp);
            const floatx4u c4 = *(const floatx4u*)cp;
            const floatx4u n4 = *(const floatx4u*)np;

            const float d0 = c4.x - n4.x + b;
            const float d1 = c4.y - n4.y + b;
            const float d2 = c4.z - n4.z + b;
            const float d3 = c4.w - n4.w + b;

            a0 += w4.x * d0 * d0;
            a1 += w4.y * d1 * d1;
            a2 += w4.z * d2 * d2;
            a3 += w4.w * d3 * d3;

            wp += 2 * ROW4;                   // next 2 rows: contiguous stream
            cp += 2 * Ww;
            np += 2 * Ww;
        }
        acc += (a0 + a1) + (a2 + a3);
    }

    const float bsum = block_reduce_256(acc);
    if (t == 0) partial[blockIdx.x] = bsum;
}

__global__ __launch_bounds__(TPB) void finalize_kernel(
        const float* __restrict__ partial,
        float* __restrict__ out)
{
    float v = 0.f;
    for (int idx = threadIdx.x; idx < NBLK; idx += TPB) v += partial[idx];
    const float s = block_reduce_256(v);
    if (threadIdx.x == 0) out[0] = s * SCALE_S;
}

extern "C" void kernel_launch(void* const* d_in, const int* in_sizes, int n_in,
                              void* d_out, int out_size, void* d_ws, size_t ws_size,
                              hipStream_t stream) {
    const float* outp = (const float*)d_in[0];   // output (512,512)
    const float* targ = (const float*)d_in[1];   // target (512,512)
    const float* w    = (const float*)d_in[2];   // w_ij (440,492,492)
    const float* bias = (const float*)d_in[3];   // bias (440,)

    float* partial = (float*)d_ws;               // NBLK partials

    main_kernel<<<NBLK, TPB, 0, stream>>>(outp, targ, w, bias, partial);
    finalize_kernel<<<1, TPB, 0, stream>>>(partial, (float*)d_out);
}

// Round 2
// 560.866 us; speedup vs baseline: 1.0037x; 1.0037x over previous
//
#include <hip/hip_runtime.h>

// Problem constants (from reference)
constexpr int Kk   = 21;
constexpr int Hh   = 512, Ww = 512;
constexpr int HO   = 492, WO = 492;          // valid conv output dims
constexpr int Cc   = 10;                     // center offset
constexpr int CTRi = 220;                    // center channel idx (dropped)
constexpr int NCH  = 440;                    // K*K - 1
constexpr int ROW4 = WO / 4;                 // 123 float4 per w row (exact, 16B aligned)
constexpr int N4F  = Hh * Ww / 4;            // 65,536 float4s for fidelity

// Persistent-grid sweep: job v = (plane, row-pair), jobs ordered contiguously
// in w. v = it*NBLK + blockIdx -> the ~1024 resident blocks always process
// ~1024 CONSECUTIVE jobs = one contiguous ~4 MB frontier sweeping w linearly.
constexpr int JPP  = HO / 2;                 // 246 row-pair jobs per plane
constexpr int JOBS = NCH * JPP;              // 108,240 jobs
constexpr int NBLK = 1024;                   // persistent blocks (16 waves/CU)

constexpr float SCALE_S  = (float)((512.0 * 512.0 * 128.0) / (440.0 * 492.0 * 492.0));
constexpr float FID_RATIO = (float)((1.0 / (512.0 * 512.0)) /
                                    ((512.0 * 512.0 * 128.0) / (440.0 * 492.0 * 492.0)));

typedef float floatx4  __attribute__((ext_vector_type(4)));              // 16B aligned
typedef float floatx4u __attribute__((ext_vector_type(4), aligned(4)));  // unaligned-ok

#define TPB 256

__device__ __forceinline__ float block_reduce_256(float v) {
    #pragma unroll
    for (int off = 32; off; off >>= 1) v += __shfl_down(v, off, 64);
    __shared__ float smem[TPB / 64];
    const int lane = threadIdx.x & 63;
    const int wid  = threadIdx.x >> 6;
    if (lane == 0) smem[wid] = v;
    __syncthreads();
    float r = 0.f;
    if (threadIdx.x == 0) {
        #pragma unroll
        for (int k = 0; k < TPB / 64; ++k) r += smem[k];
    }
    return r;
}

// Persistent kernel: grid-stride over jobs, interleaved so concurrent blocks
// read CONSECUTIVE 3936B chunks of w (one sweeping frontier chip-wide).
// Job geometry (plane, rp, ki, kj, bias) is block-uniform -> SALU.
// Lanes 246..255 are masked by multiply (branch-free; loads stay pipelined).
__global__ __launch_bounds__(TPB) void main_kernel(
        const float* __restrict__ outp,
        const float* __restrict__ targ,
        const float* __restrict__ w,
        const float* __restrict__ bias,
        float* __restrict__ partial)
{
    const int t = threadIdx.x;
    float acc = 0.f;

    // ---- fused fidelity: first N4F global threads take one float4 each ----
    {
        const int fq = blockIdx.x * TPB + t;
        if (fq < N4F) {
            const floatx4 a  = ((const floatx4*)outp)[fq];
            const floatx4 tg = ((const floatx4*)targ)[fq];
            const float d0 = a.x - tg.x, d1 = a.y - tg.y,
                        d2 = a.z - tg.z, d3 = a.w - tg.w;
            acc = (d0 * d0 + d1 * d1 + d2 * d2 + d3 * d3) * FID_RATIO;
        }
    }

    // ---- smooth term: sweeping-frontier grid-stride over (plane,row-pair) ----
    const int  te  = (t < 2 * ROW4) ? t : (2 * ROW4 - 1);   // clamp dup lanes
    const float mk = (t < 2 * ROW4) ? 1.f : 0.f;            // mask their sum
    const int  r   = (te >= ROW4) ? 1 : 0;                  // which of the 2 rows
    const int  j   = 4 * (te - r * ROW4);                   // col in floats
    const int  co  = (r + Cc) * Ww + Cc + j;                // center offset sans row-pair part

    float a0 = 0.f, a1 = 0.f, a2 = 0.f, a3 = 0.f;

    #pragma unroll 2
    for (int v = blockIdx.x; v < JOBS; v += NBLK) {
        const int plane = v / JPP;                          // uniform (SALU magic)
        const int rp    = v - plane * JPP;
        const int kk    = plane + (plane >= CTRi ? 1 : 0);  // skip dropped center
        const int ki    = kk / Kk;
        const int kj    = kk - ki * Kk;
        const float b   = bias[plane];

        // w: job v owns float4s [v*246, v*246+246) -- contiguous across v
        const floatx4 w4 = __builtin_nontemporal_load(
                (const floatx4*)w + (long)v * (2 * ROW4) + te);

        const float* base = outp + 2 * rp * Ww;
        const floatx4u c4 = *(const floatx4u*)(base + co);
        const floatx4u n4 = *(const floatx4u*)(base + (r + ki) * Ww + kj + j);

        const float wm0 = w4.x * mk, wm1 = w4.y * mk,
                    wm2 = w4.z * mk, wm3 = w4.w * mk;

        const float d0 = c4.x - n4.x + b;
        const float d1 = c4.y - n4.y + b;
        const float d2 = c4.z - n4.z + b;
        const float d3 = c4.w - n4.w + b;

        a0 += wm0 * d0 * d0;
        a1 += wm1 * d1 * d1;
        a2 += wm2 * d2 * d2;
        a3 += wm3 * d3 * d3;
    }
    acc += (a0 + a1) + (a2 + a3);

    const float bsum = block_reduce_256(acc);
    if (t == 0) partial[blockIdx.x] = bsum;
}

__global__ __launch_bounds__(TPB) void finalize_kernel(
        const float* __restrict__ partial,
        float* __restrict__ out)
{
    float v = 0.f;
    for (int idx = threadIdx.x; idx < NBLK; idx += TPB) v += partial[idx];
    const float s = block_reduce_256(v);
    if (threadIdx.x == 0) out[0] = s * SCALE_S;
}

extern "C" void kernel_launch(void* const* d_in, const int* in_sizes, int n_in,
                              void* d_out, int out_size, void* d_ws, size_t ws_size,
                              hipStream_t stream) {
    const float* outp = (const float*)d_in[0];   // output (512,512)
    const float* targ = (const float*)d_in[1];   // target (512,512)
    const float* w    = (const float*)d_in[2];   // w_ij (440,492,492)
    const float* bias = (const float*)d_in[3];   // bias (440,)

    float* partial = (float*)d_ws;               // NBLK partials

    main_kernel<<<NBLK, TPB, 0, stream>>>(outp, targ, w, bias, partial);
    finalize_kernel<<<1, TPB, 0, stream>>>(partial, (float*)d_out);
}

// Round 3
// 551.386 us; speedup vs baseline: 1.0210x; 1.0172x over previous
//
#include <hip/hip_runtime.h>

// Problem constants (from reference)
constexpr int Kk   = 21;
constexpr int Hh   = 512, Ww = 512;
constexpr int HO   = 492, WO = 492;          // valid conv output dims
constexpr int Cc   = 10;                     // center offset
constexpr int CTRi = 220;                    // center channel idx (dropped)
constexpr int NCH  = 440;                    // K*K - 1
constexpr int ROW4 = WO / 4;                 // 123 float4 per w row (exact, 16B aligned)
constexpr int N4F  = Hh * Ww / 4;            // 65,536 float4s for fidelity

constexpr int RSPLIT = HO / 2;               // 246 row-blocks, 2 rows each
constexpr int CSPLIT = 8;                    // channel splits
constexpr int NPB    = NCH / CSPLIT;         // 55 channels per block
constexpr int NBLK   = RSPLIT * CSPLIT;      // 1968 blocks

constexpr float SCALE_S  = (float)((512.0 * 512.0 * 128.0) / (440.0 * 492.0 * 492.0));
constexpr float FID_RATIO = (float)((1.0 / (512.0 * 512.0)) /
                                    ((512.0 * 512.0 * 128.0) / (440.0 * 492.0 * 492.0)));

typedef float floatx4  __attribute__((ext_vector_type(4)));              // 16B aligned
typedef float floatx4u __attribute__((ext_vector_type(4), aligned(4)));  // unaligned-ok

#define TPB 256

__device__ __forceinline__ float block_reduce_256(float v) {
    #pragma unroll
    for (int off = 32; off; off >>= 1) v += __shfl_down(v, off, 64);
    __shared__ float smem[TPB / 64];
    const int lane = threadIdx.x & 63;
    const int wid  = threadIdx.x >> 6;
    if (lane == 0) smem[wid] = v;
    __syncthreads();
    float r = 0.f;
    if (threadIdx.x == 0) {
        #pragma unroll
        for (int k = 0; k < TPB / 64; ++k) r += smem[k];
    }
    return r;
}

// r0 structure (best measured), single change: w is loaded with a PLAIN
// global_load_dwordx4 instead of __builtin_nontemporal_load. Theory: the nt
// flag defeats line-granular TCC coalescing (16B granules -> 1/4 effective
// HBM BW; 426MB/255us = 1.67 TB/s = exactly 1/4 of the fill's 6.6 TB/s).
// outp (1MB) stays L3-resident even with w streaming through the caches.
__global__ __launch_bounds__(TPB) void main_kernel(
        const float* __restrict__ outp,
        const float* __restrict__ targ,
        const float* __restrict__ w,
        const float* __restrict__ bias,
        float* __restrict__ partial)
{
    const int t = threadIdx.x;
    float acc = 0.f;

    // ---- fused fidelity: first N4F global threads take one float4 each ----
    {
        const int fq = blockIdx.x * TPB + t;
        if (fq < N4F) {
            const floatx4 a  = ((const floatx4*)outp)[fq];
            const floatx4 tg = ((const floatx4*)targ)[fq];
            const float d0 = a.x - tg.x, d1 = a.y - tg.y,
                        d2 = a.z - tg.z, d3 = a.w - tg.w;
            acc = (d0 * d0 + d1 * d1 + d2 * d2 + d3 * d3) * FID_RATIO;
        }
    }

    // ---- smooth term ----
    const int rowblk = blockIdx.x % RSPLIT;
    const int csplit = blockIdx.x / RSPLIT;
    const int n0     = csplit * NPB;

    if (t < 2 * ROW4) {                       // 246 active threads
        const int di = (t >= ROW4) ? 1 : 0;
        const int j4 = t - di * ROW4;
        const int i  = rowblk * 2 + di;       // w-plane row
        const int j  = 4 * j4;                // w-plane col (float units)

        // center taps: invariant over all channels
        const float* crow = outp + (i + Cc) * Ww + (Cc + j);
        const float c0 = crow[0], c1 = crow[1], c2 = crow[2], c3 = crow[3];

        const float* obase = outp + i * Ww + j;    // + ki*Ww + kj gives neighbor
        const floatx4* wp  = (const floatx4*)w + ((long)(n0 * HO + i) * ROW4 + j4);

        float a0 = 0.f, a1 = 0.f, a2 = 0.f, a3 = 0.f;
        #pragma unroll 5
        for (int n = n0; n < n0 + NPB; ++n, wp += HO * ROW4) {
            const int kk = n + (n >= CTRi ? 1 : 0);   // skip dropped center chan
            const int ki = kk / Kk;
            const int kj = kk - ki * Kk;

            const floatx4  w4 = *wp;                  // PLAIN load (A/B vs nt)
            const float    b  = bias[n];                              // uniform
            const floatx4u n4 = *(const floatx4u*)(obase + ki * Ww + kj);

            const float d0 = c0 - n4.x + b;
            const float d1 = c1 - n4.y + b;
            const float d2 = c2 - n4.z + b;
            const float d3 = c3 - n4.w + b;

            a0 += w4.x * d0 * d0;
            a1 += w4.y * d1 * d1;
            a2 += w4.z * d2 * d2;
            a3 += w4.w * d3 * d3;
        }
        acc += (a0 + a1) + (a2 + a3);
    }

    const float bsum = block_reduce_256(acc);
    if (t == 0) partial[blockIdx.x] = bsum;
}

__global__ __launch_bounds__(TPB) void finalize_kernel(
        const float* __restrict__ partial,
        float* __restrict__ out)
{
    float v = 0.f;
    for (int idx = threadIdx.x; idx < NBLK; idx += TPB) v += partial[idx];
    const float s = block_reduce_256(v);
    if (threadIdx.x == 0) out[0] = s * SCALE_S;
}

extern "C" void kernel_launch(void* const* d_in, const int* in_sizes, int n_in,
                              void* d_out, int out_size, void* d_ws, size_t ws_size,
                              hipStream_t stream) {
    const float* outp = (const float*)d_in[0];   // output (512,512)
    const float* targ = (const float*)d_in[1];   // target (512,512)
    const float* w    = (const float*)d_in[2];   // w_ij (440,492,492)
    const float* bias = (const float*)d_in[3];   // bias (440,)

    float* partial = (float*)d_ws;               // NBLK partials

    main_kernel<<<NBLK, TPB, 0, stream>>>(outp, targ, w, bias, partial);
    finalize_kernel<<<1, TPB, 0, stream>>>(partial, (float*)d_out);
}